// Round 1
// baseline (421.760 us; speedup 1.0000x reference)
//
#include <hip/hip_runtime.h>
#include <hip/hip_bf16.h>

#define FDIM 64
#define H 256
#define W 256
#define N_PIXELS (H * W)
#define PIX_PER_BLOCK 4

// One wave (64 lanes) per pixel; lane = feature dim.
// Chunked broadcast: each lane owns one CSR entry of the chunk, computes
// scale = cnt * exp(gamma[idx]); then all 64 entries are broadcast via
// v_readlane (wave-uniform loop index -> SGPR broadcast) and accumulated.
__global__ __launch_bounds__(PIX_PER_BLOCK * 64) void sgstem_kernel(
    const int* __restrict__ indices,
    const float* __restrict__ cnts,
    const int* __restrict__ indptr,
    const float* __restrict__ gamma,
    const float* __restrict__ tokens,
    float* __restrict__ out)
{
    const int lane  = threadIdx.x & 63;
    const int wave  = threadIdx.x >> 6;
    const int pixel = blockIdx.x * PIX_PER_BLOCK + wave;
    if (pixel >= N_PIXELS) return;

    const int start = indptr[pixel];
    const int end   = indptr[pixel + 1];

    float acc = 0.0f;

    for (int base = start; base < end; base += 64) {
        const int e = base + lane;
        int   idx   = 0;
        float scale = 0.0f;
        if (e < end) {
            idx   = indices[e];
            scale = cnts[e] * __expf(gamma[idx]);
        }
        const int m = min(64, end - base);
        #pragma unroll 8
        for (int i = 0; i < m; ++i) {
            const int   gi = __builtin_amdgcn_readlane(idx, i);
            const int   sb = __builtin_amdgcn_readlane(__float_as_int(scale), i);
            const float s  = __int_as_float(sb);
            acc = fmaf(tokens[gi * FDIM + lane], s, acc);
        }
    }

    out[pixel * FDIM + lane] = acc;
}

extern "C" void kernel_launch(void* const* d_in, const int* in_sizes, int n_in,
                              void* d_out, int out_size, void* d_ws, size_t ws_size,
                              hipStream_t stream) {
    const int*   indices = (const int*)d_in[0];
    const float* cnts    = (const float*)d_in[1];
    const int*   indptr  = (const int*)d_in[2];
    const float* gamma   = (const float*)d_in[3];
    const float* tokens  = (const float*)d_in[4];
    float*       out     = (float*)d_out;

    const int nblocks = N_PIXELS / PIX_PER_BLOCK;  // 16384
    sgstem_kernel<<<nblocks, PIX_PER_BLOCK * 64, 0, stream>>>(
        indices, cnts, indptr, gamma, tokens, out);
}

// Round 2
// 178.182 us; speedup vs baseline: 2.3670x; 2.3670x over previous
//
#include <hip/hip_runtime.h>
#include <hip/hip_bf16.h>

#define FDIM 64
#define N_PIXELS 65536
#define WAVES_PER_BLOCK 4

// One wave per pixel. Inner loop processes 4 CSR entries in parallel:
// 16-lane group g handles entry j*4+g, each lane loading a float4 slice of
// the 64-float token row. Chunk metadata (idx, scale) staged through LDS
// (one coalesced load per lane per 64-entry chunk, ds_read_b64 broadcast in
// the inner loop). Full chunks use a compile-time trip count for MLP.
__global__ __launch_bounds__(WAVES_PER_BLOCK * 64) void sgstem_kernel(
    const int* __restrict__ indices,
    const float* __restrict__ cnts,
    const int* __restrict__ indptr,
    const float* __restrict__ gamma,
    const float4* __restrict__ tokens4,   // (N_GENES, 16) float4 view
    float4* __restrict__ out4)            // (N_PIXELS, 16) float4 view
{
    __shared__ int2 meta[WAVES_PER_BLOCK][64];   // {idx, scale_bits}

    const int lane = threadIdx.x & 63;
    const int wave = threadIdx.x >> 6;
    const int g    = lane >> 4;    // entry group 0..3
    const int fl   = lane & 15;    // float4 slot within token row
    const int pixel = blockIdx.x * WAVES_PER_BLOCK + wave;

    const int start = indptr[pixel];
    const int end   = indptr[pixel + 1];

    float4 acc = {0.f, 0.f, 0.f, 0.f};

    for (int base = start; base < end; base += 64) {
        // stage this chunk's metadata: lane owns entry base+lane
        const int e = base + lane;
        int   idx   = 0;
        float scale = 0.0f;
        if (e < end) {
            idx   = indices[e];
            scale = cnts[e] * __expf(gamma[idx]);
        }
        int2 mt;
        mt.x = idx;
        mt.y = __float_as_int(scale);
        meta[wave][lane] = mt;   // wave-private region; waitcnt orders w/ reads

        const int m = end - base;
        if (m >= 64) {
            #pragma unroll 8
            for (int j = 0; j < 16; ++j) {
                const int2 mm = meta[wave][j * 4 + g];
                const float s = __int_as_float(mm.y);
                const float4 t = tokens4[mm.x * 16 + fl];
                acc.x = fmaf(t.x, s, acc.x);
                acc.y = fmaf(t.y, s, acc.y);
                acc.z = fmaf(t.z, s, acc.z);
                acc.w = fmaf(t.w, s, acc.w);
            }
        } else {
            const int niter = (m + 3) >> 2;   // invalid entries have scale=0
            for (int j = 0; j < niter; ++j) {
                const int2 mm = meta[wave][j * 4 + g];
                const float s = __int_as_float(mm.y);
                const float4 t = tokens4[mm.x * 16 + fl];
                acc.x = fmaf(t.x, s, acc.x);
                acc.y = fmaf(t.y, s, acc.y);
                acc.z = fmaf(t.z, s, acc.z);
                acc.w = fmaf(t.w, s, acc.w);
            }
        }
    }

    // reduce the 4 groups (same feature slice fl in each group)
    acc.x += __shfl_xor(acc.x, 16);
    acc.y += __shfl_xor(acc.y, 16);
    acc.z += __shfl_xor(acc.z, 16);
    acc.w += __shfl_xor(acc.w, 16);
    acc.x += __shfl_xor(acc.x, 32);
    acc.y += __shfl_xor(acc.y, 32);
    acc.z += __shfl_xor(acc.z, 32);
    acc.w += __shfl_xor(acc.w, 32);

    if (g == 0) {
        out4[pixel * 16 + fl] = acc;   // 16 lanes x 16 B = 256 B coalesced
    }
}

extern "C" void kernel_launch(void* const* d_in, const int* in_sizes, int n_in,
                              void* d_out, int out_size, void* d_ws, size_t ws_size,
                              hipStream_t stream) {
    const int*    indices = (const int*)d_in[0];
    const float*  cnts    = (const float*)d_in[1];
    const int*    indptr  = (const int*)d_in[2];
    const float*  gamma   = (const float*)d_in[3];
    const float4* tokens4 = (const float4*)d_in[4];
    float4*       out4    = (float4*)d_out;

    const int nblocks = N_PIXELS / WAVES_PER_BLOCK;  // 16384
    sgstem_kernel<<<nblocks, WAVES_PER_BLOCK * 64, 0, stream>>>(
        indices, cnts, indptr, gamma, tokens4, out4);
}

// Round 3
// 165.332 us; speedup vs baseline: 2.5510x; 1.0777x over previous
//
#include <hip/hip_runtime.h>
#include <hip/hip_bf16.h>

#define FDIM 64
#define N_PIXELS 65536
#define N_GENES 30000
#define WAVES_PER_BLOCK 4
#define PIX_PER_WAVE 8

// ---------- kernel A: f32 tokens -> bf16 table in ws (RNE) ----------
__device__ __forceinline__ unsigned short f32_to_bf16_rne(float f) {
    unsigned int u = __float_as_uint(f);
    u = (u + 0x7FFFu + ((u >> 16) & 1u)) >> 16;
    return (unsigned short)u;
}

__global__ __launch_bounds__(256) void convert_tokens(
    const float4* __restrict__ tokens4,   // 480000 float4
    ushort4* __restrict__ tok_bf)         // 480000 ushort4 (bf16)
{
    const int i = blockIdx.x * blockDim.x + threadIdx.x;   // exactly 480000
    const float4 t = tokens4[i];
    ushort4 o;
    o.x = f32_to_bf16_rne(t.x);
    o.y = f32_to_bf16_rne(t.y);
    o.z = f32_to_bf16_rne(t.z);
    o.w = f32_to_bf16_rne(t.w);
    tok_bf[i] = o;
}

// ---------- kernel B: main gather-scatter ----------
// One wave per 8 consecutive pixels. Per 64-entry chunk: each lane stages
// (idx, cnt*exp(gamma)) to LDS; inner loop processes 8 entries in parallel
// (8-lane groups), each lane loading uint4 = 8 bf16 of the token row.
__global__ __launch_bounds__(WAVES_PER_BLOCK * 64) void sgstem_main(
    const int* __restrict__ indices,
    const float* __restrict__ cnts,
    const int* __restrict__ indptr,
    const float* __restrict__ gamma,
    const uint4* __restrict__ tok_bf,     // (N_GENES, 8) uint4 rows, 128 B each
    float4* __restrict__ out4)            // (N_PIXELS, 16) float4
{
    __shared__ int2 meta[WAVES_PER_BLOCK][64];   // {idx, scale_bits}

    const int lane = threadIdx.x & 63;
    const int wave = threadIdx.x >> 6;
    const int g    = lane >> 3;          // entry slot 0..7
    const int fl   = lane & 7;           // uint4 slot in token row
    const int wgid = blockIdx.x * WAVES_PER_BLOCK + wave;   // 0..8191
    const int p0   = wgid * PIX_PER_WAVE;

    for (int pixel = p0; pixel < p0 + PIX_PER_WAVE; ++pixel) {
        const int start = indptr[pixel];
        const int end   = indptr[pixel + 1];

        float a0 = 0.f, a1 = 0.f, a2 = 0.f, a3 = 0.f;
        float a4 = 0.f, a5 = 0.f, a6 = 0.f, a7 = 0.f;

        for (int base = start; base < end; base += 64) {
            const int e = base + lane;
            int   idx   = 0;
            float scale = 0.0f;
            if (e < end) {
                idx   = indices[e];
                scale = cnts[e] * __expf(gamma[idx]);
            }
            int2 mt;
            mt.x = idx;
            mt.y = __float_as_int(scale);
            meta[wave][lane] = mt;       // wave-private; lgkmcnt orders it

            const int m = end - base;
            if (m >= 64) {
                #pragma unroll 8
                for (int j = 0; j < 8; ++j) {
                    const int2 mm = meta[wave][j * 8 + g];
                    const float s = __int_as_float(mm.y);
                    const uint4 t = tok_bf[mm.x * 8 + fl];
                    a0 = fmaf(__uint_as_float(t.x << 16), s, a0);
                    a1 = fmaf(__uint_as_float(t.x & 0xFFFF0000u), s, a1);
                    a2 = fmaf(__uint_as_float(t.y << 16), s, a2);
                    a3 = fmaf(__uint_as_float(t.y & 0xFFFF0000u), s, a3);
                    a4 = fmaf(__uint_as_float(t.z << 16), s, a4);
                    a5 = fmaf(__uint_as_float(t.z & 0xFFFF0000u), s, a5);
                    a6 = fmaf(__uint_as_float(t.w << 16), s, a6);
                    a7 = fmaf(__uint_as_float(t.w & 0xFFFF0000u), s, a7);
                }
            } else {
                const int niter = (m + 7) >> 3;   // invalid entries: scale=0
                for (int j = 0; j < niter; ++j) {
                    const int2 mm = meta[wave][j * 8 + g];
                    const float s = __int_as_float(mm.y);
                    const uint4 t = tok_bf[mm.x * 8 + fl];
                    a0 = fmaf(__uint_as_float(t.x << 16), s, a0);
                    a1 = fmaf(__uint_as_float(t.x & 0xFFFF0000u), s, a1);
                    a2 = fmaf(__uint_as_float(t.y << 16), s, a2);
                    a3 = fmaf(__uint_as_float(t.y & 0xFFFF0000u), s, a3);
                    a4 = fmaf(__uint_as_float(t.z << 16), s, a4);
                    a5 = fmaf(__uint_as_float(t.z & 0xFFFF0000u), s, a5);
                    a6 = fmaf(__uint_as_float(t.w << 16), s, a6);
                    a7 = fmaf(__uint_as_float(t.w & 0xFFFF0000u), s, a7);
                }
            }
        }

        // reduce across the 8 entry-groups (lane bits 3..5)
        #pragma unroll
        for (int mask = 8; mask <= 32; mask <<= 1) {
            a0 += __shfl_xor(a0, mask);
            a1 += __shfl_xor(a1, mask);
            a2 += __shfl_xor(a2, mask);
            a3 += __shfl_xor(a3, mask);
            a4 += __shfl_xor(a4, mask);
            a5 += __shfl_xor(a5, mask);
            a6 += __shfl_xor(a6, mask);
            a7 += __shfl_xor(a7, mask);
        }

        if (g == 0) {
            float4 lo = make_float4(a0, a1, a2, a3);
            float4 hi = make_float4(a4, a5, a6, a7);
            out4[pixel * 16 + fl * 2]     = lo;   // 8 lanes x 32 B = 256 B
            out4[pixel * 16 + fl * 2 + 1] = hi;
        }
    }
}

extern "C" void kernel_launch(void* const* d_in, const int* in_sizes, int n_in,
                              void* d_out, int out_size, void* d_ws, size_t ws_size,
                              hipStream_t stream) {
    const int*    indices = (const int*)d_in[0];
    const float*  cnts    = (const float*)d_in[1];
    const int*    indptr  = (const int*)d_in[2];
    const float*  gamma   = (const float*)d_in[3];
    const float4* tokens4 = (const float4*)d_in[4];
    float4*       out4    = (float4*)d_out;

    ushort4* tok_bf = (ushort4*)d_ws;   // 3.84 MB bf16 token table

    // A: convert tokens (30000*64 = 1,920,000 f32 -> 480,000 ushort4)
    convert_tokens<<<1875, 256, 0, stream>>>(tokens4, tok_bf);

    // B: main kernel — 8192 waves x 8 pixels
    const int nblocks = N_PIXELS / (WAVES_PER_BLOCK * PIX_PER_WAVE);  // 2048
    sgstem_main<<<nblocks, WAVES_PER_BLOCK * 64, 0, stream>>>(
        indices, cnts, indptr, gamma, (const uint4*)tok_bf, out4);
}